// Round 6
// baseline (1226.594 us; speedup 1.0000x reference)
//
#include <hip/hip_runtime.h>
#include <hip/hip_bf16.h>

// Swin stage: B=64 H=W=56 D=128 WS=7 NH=4 L=2 HID=512, downsample 4D->2D.
// Round 6: fusion round. bf16 residual stream x_ws; MLP1+MLP2 fused in one
// kernel (H never touches HBM); LN2 fused into proj epilogue; LN1(layer1)
// fused into MLP epilogue (shifted-window scatter). GEMM core = r5 structure.

typedef short bf16x8 __attribute__((ext_vector_type(8)));
typedef float f32x4 __attribute__((ext_vector_type(4)));
typedef unsigned short u16;
typedef unsigned int u32;

#define MTOK 200704   // B*H*W tokens
#define DSTOK 50176   // B*28*28

__device__ __forceinline__ u16 f2b(float f){
  u32 u = __float_as_uint(f);
  u += 0x7fffu + ((u >> 16) & 1u);
  return (u16)(u >> 16);
}
__device__ __forceinline__ float blo(u32 u){ return __uint_as_float(u << 16); }
__device__ __forceinline__ float bhi(u32 u){ return __uint_as_float(u & 0xffff0000u); }
__device__ __forceinline__ float b2f(u16 u){ return __uint_as_float(((u32)u) << 16); }

__device__ __forceinline__ float gelu_tanh(float v){
  float u = 0.7978845608028654f * (v + 0.044715f * v * v * v);
  u = fminf(u, 10.f);
  float e = __expf(2.f * u);
  float t = (e - 1.f) / (e + 1.f);
  return 0.5f * v * (1.f + t);
}

#define GLDS(gp, lp) __builtin_amdgcn_global_load_lds( \
    (const __attribute__((address_space(1))) u32*)(gp), \
    (__attribute__((address_space(3))) u32*)(lp), 16, 0, 0)

// ---------------- weight transpose + bf16 cast: src[K][N] f32 -> dst[N][K] bf16
__global__ void transpose_cvt(const float* __restrict__ src, u16* __restrict__ dst,
                              int K, int N){
  int e = blockIdx.x * 256 + threadIdx.x;
  if (e >= K * N) return;
  int k = e / N, n = e - k * N;
  dst[n * K + k] = f2b(src[e]);
}

// ---------------- LN1 layer0: f32 src, window-order gather -> bf16 rows
__global__ __launch_bounds__(256) void ln0_kernel(const float* __restrict__ src,
    const float* __restrict__ gw, const float* __restrict__ bw,
    u16* __restrict__ dst)
{
  int wv = threadIdx.x >> 6, lane = threadIdx.x & 63;
  int t = blockIdx.x * 4 + wv;
  int n = t % 49; int tq = t / 49; int gg = tq & 63; int b_ = tq >> 6;
  int r = n / 7, c = n - 7 * r;
  int h = (gg >> 3) * 7 + r, w = (gg & 7) * 7 + c;
  long soff = ((long)((b_ * 56 + h) * 56 + w)) * 128;
  float2 v = *(const float2*)(src + soff + lane * 2);
  float s = v.x + v.y, s2 = v.x * v.x + v.y * v.y;
  #pragma unroll
  for (int o = 32; o; o >>= 1) { s += __shfl_xor(s, o); s2 += __shfl_xor(s2, o); }
  float mean = s * 0.0078125f;
  float var  = s2 * 0.0078125f - mean * mean;
  float rstd = rsqrtf(var + 1e-5f);
  int c0 = lane * 2;
  ushort2 o2;
  o2.x = f2b((v.x - mean) * rstd * gw[c0]   + bw[c0]);
  o2.y = f2b((v.y - mean) * rstd * gw[c0+1] + bw[c0+1]);
  *(ushort2*)(dst + (long)t * 128 + c0) = o2;
}

// ---------------- downsample gather (bf16 src) + LN(512) -> bf16 rows
__global__ __launch_bounds__(256) void ds_ln_kernel(const u16* __restrict__ x,
    const float* __restrict__ gw, const float* __restrict__ bw,
    u16* __restrict__ dst)
{
  int wv = threadIdx.x >> 6, lane = threadIdx.x & 63;
  int t = blockIdx.x * 4 + wv;
  int j = t % 28; int tq = t / 28; int i = tq % 28; int b_ = tq / 28;
  int e0 = lane * 8;
  int p = e0 >> 8, q = (e0 >> 7) & 1, d = e0 & 127;
  const u16* src = x + ((long)((b_ * 56 + 2*i + p) * 56 + 2*j + q)) * 128 + d;
  uint4 a = *(const uint4*)src;
  float vs[8] = {blo(a.x), bhi(a.x), blo(a.y), bhi(a.y),
                 blo(a.z), bhi(a.z), blo(a.w), bhi(a.w)};
  float s = 0.f, s2 = 0.f;
  #pragma unroll
  for (int u = 0; u < 8; u++) { s += vs[u]; s2 += vs[u] * vs[u]; }
  #pragma unroll
  for (int o = 32; o; o >>= 1) { s += __shfl_xor(s, o); s2 += __shfl_xor(s2, o); }
  float mean = s * (1.f / 512.f);
  float var  = s2 * (1.f / 512.f) - mean * mean;
  float rstd = rsqrtf(var + 1e-5f);
  u16 ov[8];
  #pragma unroll
  for (int u = 0; u < 8; u++) ov[u] = f2b((vs[u] - mean) * rstd * gw[e0+u] + bw[e0+u]);
  uint4 o4;
  o4.x = (u32)ov[0] | ((u32)ov[1] << 16);
  o4.y = (u32)ov[2] | ((u32)ov[3] << 16);
  o4.z = (u32)ov[4] | ((u32)ov[5] << 16);
  o4.w = (u32)ov[6] | ((u32)ov[7] << 16);
  *(uint4*)(dst + (long)t * 512 + e0) = o4;
}

// ---------------- MFMA window attention (unchanged from round 4)
template<int MASKED>
__global__ __launch_bounds__(256) void attn_mfma(const u16* __restrict__ qkv,
                                                 u16* __restrict__ obuf)
{
  __shared__ u16 Pls_all[4][64][72];
  const int h = threadIdx.x >> 6;
  const int lane = threadIdx.x & 63;
  const int c = lane & 15, g = lane >> 4;
  const int wi = blockIdx.x;
  const int g_ = wi & 63;
  const long t0 = (long)wi * 49;
  u16 (*Pls)[72] = Pls_all[h];

  bf16x8 qf[4], kf[4];
  #pragma unroll
  for (int mi = 0; mi < 4; mi++) {
    int r = 16*mi + c; r = r > 48 ? 48 : r;
    qf[mi] = *(const bf16x8*)(qkv + (t0 + r)*384 + h*32 + g*8);
  }
  #pragma unroll
  for (int ni = 0; ni < 4; ni++) {
    int r = 16*ni + c; r = r > 48 ? 48 : r;
    kf[ni] = *(const bf16x8*)(qkv + (t0 + r)*384 + 128 + h*32 + g*8);
  }

  f32x4 acc[4][4];
  const f32x4 zero4 = {0.f, 0.f, 0.f, 0.f};
  #pragma unroll
  for (int mi = 0; mi < 4; mi++)
    #pragma unroll
    for (int ni = 0; ni < 4; ni++)
      acc[mi][ni] = __builtin_amdgcn_mfma_f32_16x16x32_bf16(qf[mi], kf[ni], zero4, 0, 0, 0);

  bf16x8 vf[2][2];
  #pragma unroll
  for (int ni2 = 0; ni2 < 2; ni2++)
    #pragma unroll
    for (int ks = 0; ks < 2; ks++)
      #pragma unroll
      for (int jj = 0; jj < 8; jj++) {
        int k = ks*32 + 8*g + jj; k = k > 48 ? 48 : k;
        vf[ni2][ks][jj] = (short)qkv[(t0 + k)*384 + 256 + h*32 + 16*ni2 + c];
      }

  int rid_c[4];
  int g1b = 0, g2b = 0;
  if (MASKED) {
    g1b = (g_ >> 3) * 7; g2b = (g_ & 7) * 7;
    #pragma unroll
    for (int ni = 0; ni < 4; ni++) {
      int col = 16*ni + c; col = col > 48 ? 48 : col;
      int cr = col / 7, cc = col - 7*cr;
      int hh = g1b + cr, ww = g2b + cc;
      rid_c[ni] = (hh < 49 ? 0 : (hh < 53 ? 1 : 2)) * 3 + (ww < 49 ? 0 : (ww < 53 ? 1 : 2));
    }
  }

  #pragma unroll
  for (int mi = 0; mi < 4; mi++) {
    #pragma unroll
    for (int j = 0; j < 4; j++) {
      int rr = 16*mi + 4*g + j;
      int rid_r = 0;
      if (MASKED) {
        int r2 = rr > 48 ? 48 : rr;
        int rh = r2 / 7, rw = r2 - 7*rh;
        int hh = g1b + rh, ww = g2b + rw;
        rid_r = (hh < 49 ? 0 : (hh < 53 ? 1 : 2)) * 3 + (ww < 49 ? 0 : (ww < 53 ? 1 : 2));
      }
      float sv[4];
      #pragma unroll
      for (int ni = 0; ni < 4; ni++) {
        float s = acc[mi][ni][j] * 0.17677669529663687f;
        int col = 16*ni + c;
        if (col >= 49) s = -1e30f;
        else if (MASKED && rid_c[ni] != rid_r) s -= 100.f;
        sv[ni] = s;
      }
      float m4 = fmaxf(fmaxf(sv[0], sv[1]), fmaxf(sv[2], sv[3]));
      #pragma unroll
      for (int o = 1; o <= 8; o <<= 1) m4 = fmaxf(m4, __shfl_xor(m4, o));
      float p[4], sum = 0.f;
      #pragma unroll
      for (int ni = 0; ni < 4; ni++) { p[ni] = __expf(sv[ni] - m4); sum += p[ni]; }
      #pragma unroll
      for (int o = 1; o <= 8; o <<= 1) sum += __shfl_xor(sum, o);
      float rs = 1.f / sum;
      #pragma unroll
      for (int ni = 0; ni < 4; ni++)
        Pls[rr][16*ni + c] = f2b(p[ni] * rs);
    }
  }

  __syncthreads();

  f32x4 accO[4][2];
  #pragma unroll
  for (int mi = 0; mi < 4; mi++)
    #pragma unroll
    for (int ni2 = 0; ni2 < 2; ni2++) accO[mi][ni2] = zero4;
  #pragma unroll
  for (int mi = 0; mi < 4; mi++)
    #pragma unroll
    for (int ks = 0; ks < 2; ks++) {
      bf16x8 pa = *(const bf16x8*)(&Pls[16*mi + c][ks*32 + g*8]);
      #pragma unroll
      for (int ni2 = 0; ni2 < 2; ni2++)
        accO[mi][ni2] = __builtin_amdgcn_mfma_f32_16x16x32_bf16(pa, vf[ni2][ks], accO[mi][ni2], 0, 0, 0);
    }

  #pragma unroll
  for (int mi = 0; mi < 4; mi++)
    #pragma unroll
    for (int ni2 = 0; ni2 < 2; ni2++)
      #pragma unroll
      for (int j = 0; j < 4; j++) {
        int r = 16*mi + 4*g + j;
        if (r < 49)
          obuf[(t0 + r)*128 + h*32 + 16*ni2 + c] = f2b(accO[mi][ni2][j]);
      }
}

// ---------------- MFMA GEMM (r5 core). EPI: 0 bias->bf16 (QKV)
// 2: proj: x = res + v + bias -> bf16 x (RMW if !RESF32), fused LN2 -> lnout
// 4: plain f32 store (downsample)
template<int K, int EPI, int RESF32>
__global__ __launch_bounds__(256) void gemm_kernel(
    const u16* __restrict__ A, const u16* __restrict__ Bt,
    const float* __restrict__ bias, int Ntot,
    u16* __restrict__ outb, float* __restrict__ outf,
    u16* __restrict__ outx, const float* __restrict__ resf, int shift,
    const float* __restrict__ lng, const float* __restrict__ lnb,
    u16* __restrict__ lnout)
{
  __shared__ __align__(16) u16 sh[16384];      // 32 KB: As 16K | Bs 16K; C aliases
  u16* Asl = sh;
  u16* Bsl = sh + 8192;
  float (*Cf)[128] = (float(*)[128])sh;

  const int tid = threadIdx.x;
  const int row0 = blockIdx.x * 128, col0 = blockIdx.y * 128;
  const int wv = tid >> 6, lane = tid & 63;
  const int m_off = (wv >> 1) * 64, n_off = (wv & 1) * 64;
  const int lr = lane & 15, lk = (lane >> 4) * 8;

  f32x4 acc[4][4];
  const f32x4 zero4 = {0.f, 0.f, 0.f, 0.f};
  #pragma unroll
  for (int a1 = 0; a1 < 4; a1++)
    #pragma unroll
    for (int a2 = 0; a2 < 4; a2++) acc[a1][a2] = zero4;

  for (int k0 = 0; k0 < K; k0 += 64) {
    __syncthreads();
    #pragma unroll
    for (int j = 0; j < 4; j++) {
      int ch = tid + j * 256;
      int r = ch >> 3, cc = ch & 7;
      int col = k0 + ((cc * 8) ^ ((r & 7) << 3));
      GLDS(A  + (long)(row0 + r) * K + col, Asl + ch * 8);
      GLDS(Bt + (long)(col0 + r) * K + col, Bsl + ch * 8);
    }
    __syncthreads();
    #pragma unroll
    for (int kk = 0; kk < 64; kk += 32) {
      bf16x8 af[4], bfr[4];
      #pragma unroll
      for (int mi = 0; mi < 4; mi++) {
        int R = m_off + mi*16 + lr;
        af[mi] = *(const bf16x8*)&Asl[R*64 + ((kk + lk) ^ ((R & 7) << 3))];
      }
      #pragma unroll
      for (int ni = 0; ni < 4; ni++) {
        int R = n_off + ni*16 + lr;
        bfr[ni] = *(const bf16x8*)&Bsl[R*64 + ((kk + lk) ^ ((R & 7) << 3))];
      }
      #pragma unroll
      for (int mi = 0; mi < 4; mi++)
        #pragma unroll
        for (int ni = 0; ni < 4; ni++)
          acc[mi][ni] = __builtin_amdgcn_mfma_f32_16x16x32_bf16(
              af[mi], bfr[ni], acc[mi][ni], 0, 0, 0);
    }
  }

  const int g = lane >> 4;
  #pragma unroll
  for (int half = 0; half < 2; half++) {
    __syncthreads();
    if ((wv >> 1) == half) {
      #pragma unroll
      for (int mi = 0; mi < 4; mi++)
        #pragma unroll
        for (int ni = 0; ni < 4; ni++)
          #pragma unroll
          for (int j = 0; j < 4; j++) {
            int lrow = mi*16 + 4*g + j;
            int col  = n_off + ni*16 + lr;
            Cf[lrow][col ^ ((lrow & 7) << 2)] = acc[mi][ni][j];
          }
    }
    __syncthreads();
    #pragma unroll
    for (int jj = 0; jj < 8; jj++) {
      int ch = tid + jj * 256;
      int r = ch >> 5, c4 = ch & 31;
      float4 v = *(const float4*)&Cf[r][(c4*4) ^ ((r & 7) << 2)];
      int grow = row0 + half*64 + r;
      int gcol = col0 + c4*4;
      if (EPI == 0) {
        float4 b4 = *(const float4*)&bias[gcol];
        uint2 o2;
        o2.x = (u32)f2b(v.x + b4.x) | ((u32)f2b(v.y + b4.y) << 16);
        o2.y = (u32)f2b(v.z + b4.z) | ((u32)f2b(v.w + b4.w) << 16);
        *(uint2*)(outb + (long)grow * Ntot + gcol) = o2;
      } else if (EPI == 2) {
        // window-order row -> linear token scatter
        int n = grow % 49; int tq = grow / 49; int gg = tq & 63; int b_ = tq >> 6;
        int rr = n / 7, cc = n - 7 * rr;
        int hh = (gg >> 3) * 7 + rr, ww = (gg & 7) * 7 + cc;
        if (shift) { hh += 3; if (hh >= 56) hh -= 56; ww += 3; if (ww >= 56) ww -= 56; }
        long t = (long)(b_ * 56 + hh) * 56 + ww;     // linear token
        long obase = t * 128;
        float4 b4 = *(const float4*)&bias[gcol];
        float r0, r1, r2, r3;
        if (RESF32) {
          float4 res = *(const float4*)&resf[obase + gcol];
          r0 = res.x; r1 = res.y; r2 = res.z; r3 = res.w;
        } else {
          uint2 cur = *(const uint2*)&outx[obase + gcol];
          r0 = blo(cur.x); r1 = bhi(cur.x); r2 = blo(cur.y); r3 = bhi(cur.y);
        }
        float o0 = r0 + v.x + b4.x, o1 = r1 + v.y + b4.y;
        float o2v = r2 + v.z + b4.z, o3 = r3 + v.w + b4.w;
        uint2 xw;
        xw.x = (u32)f2b(o0) | ((u32)f2b(o1) << 16);
        xw.y = (u32)f2b(o2v) | ((u32)f2b(o3) << 16);
        *(uint2*)(outx + obase + gcol) = xw;
        // fused LN2 over the 32 lanes sharing this row
        float s = o0 + o1 + o2v + o3;
        float s2 = o0*o0 + o1*o1 + o2v*o2v + o3*o3;
        #pragma unroll
        for (int o = 1; o <= 16; o <<= 1) { s += __shfl_xor(s, o); s2 += __shfl_xor(s2, o); }
        float mean = s * 0.0078125f;
        float var  = s2 * 0.0078125f - mean * mean;
        float rstd = rsqrtf(var + 1e-5f);
        float4 g4 = *(const float4*)&lng[gcol];
        float4 bb4 = *(const float4*)&lnb[gcol];
        uint2 lo2;
        lo2.x = (u32)f2b((o0 - mean) * rstd * g4.x + bb4.x) |
                ((u32)f2b((o1 - mean) * rstd * g4.y + bb4.y) << 16);
        lo2.y = (u32)f2b((o2v - mean) * rstd * g4.z + bb4.z) |
                ((u32)f2b((o3 - mean) * rstd * g4.w + bb4.w) << 16);
        *(uint2*)(lnout + obase + gcol) = lo2;
      } else {
        *(float4*)&outf[(long)grow * Ntot + gcol] = v;
      }
    }
  }
}

// ---------------- fused MLP: x += W2^T gelu(W1^T xh + b1) + b2  (per 128 rows)
// S0 = A-tile / H-tile (alternating), S1 = W1-chunk / W2-chunk. 4 chunks of 128.
// WRITE_LN: also emit LN1(x) scattered to shifted-window order (layer0 -> layer1).
template<int WRITE_LN>
__global__ __launch_bounds__(256) void mlp_kernel(
    const u16* __restrict__ xh, const u16* __restrict__ w1t, const float* __restrict__ b1,
    const u16* __restrict__ w2t, const float* __restrict__ b2,
    u16* __restrict__ xrmw,
    const float* __restrict__ lng, const float* __restrict__ lnb,
    u16* __restrict__ lnout)
{
  __shared__ __align__(16) u16 S0[16384];   // 32 KB
  __shared__ __align__(16) u16 S1[16384];   // 32 KB
  const int tid = threadIdx.x;
  const int row0 = blockIdx.x * 128;
  const int wv = tid >> 6, lane = tid & 63;
  const int m_off = (wv >> 1) * 64, n_off = (wv & 1) * 64;
  const int lr = lane & 15, lk = (lane >> 4) * 8, g = lane >> 4;

  f32x4 acc_o[4][4];
  const f32x4 zero4 = {0.f, 0.f, 0.f, 0.f};
  #pragma unroll
  for (int a1 = 0; a1 < 4; a1++)
    #pragma unroll
    for (int a2 = 0; a2 < 4; a2++) acc_o[a1][a2] = zero4;

  for (int nc = 0; nc < 4; nc++) {
    __syncthreads();                           // S0/S1 free
    #pragma unroll
    for (int j = 0; j < 8; j++) {
      int ch = tid + j * 256;                  // 2048 x 16B per buffer
      int r = ch >> 4, cc = ch & 15;
      int col = (cc * 8) ^ ((r & 7) << 3);
      GLDS(xh  + (long)(row0 + r) * 128 + col,      S0 + ch * 8);
      GLDS(w1t + (long)(nc * 128 + r) * 128 + col,  S1 + ch * 8);
    }
    __syncthreads();                           // A + W1c ready
    f32x4 acc_h[4][4];
    #pragma unroll
    for (int a1 = 0; a1 < 4; a1++)
      #pragma unroll
      for (int a2 = 0; a2 < 4; a2++) acc_h[a1][a2] = zero4;
    #pragma unroll
    for (int kk = 0; kk < 128; kk += 32) {
      bf16x8 af[4], bfr[4];
      #pragma unroll
      for (int mi = 0; mi < 4; mi++) {
        int R = m_off + mi*16 + lr;
        af[mi] = *(const bf16x8*)&S0[R*128 + ((kk + lk) ^ ((R & 7) << 3))];
      }
      #pragma unroll
      for (int ni = 0; ni < 4; ni++) {
        int R = n_off + ni*16 + lr;
        bfr[ni] = *(const bf16x8*)&S1[R*128 + ((kk + lk) ^ ((R & 7) << 3))];
      }
      #pragma unroll
      for (int mi = 0; mi < 4; mi++)
        #pragma unroll
        for (int ni = 0; ni < 4; ni++)
          acc_h[mi][ni] = __builtin_amdgcn_mfma_f32_16x16x32_bf16(
              af[mi], bfr[ni], acc_h[mi][ni], 0, 0, 0);
    }
    __syncthreads();                           // A/W1c reads done
    // H (bias+gelu, bf16) -> S0 ; stage W2 chunk -> S1
    #pragma unroll
    for (int mi = 0; mi < 4; mi++)
      #pragma unroll
      for (int ni = 0; ni < 4; ni++)
        #pragma unroll
        for (int j = 0; j < 4; j++) {
          int lrow = m_off + mi*16 + 4*g + j;
          int col  = n_off + ni*16 + lr;
          float hv = gelu_tanh(acc_h[mi][ni][j] + b1[nc*128 + col]);
          S0[lrow*128 + (col ^ ((lrow & 7) << 3))] = f2b(hv);
        }
    #pragma unroll
    for (int j = 0; j < 8; j++) {
      int ch = tid + j * 256;
      int r = ch >> 4, cc = ch & 15;
      int col = (cc * 8) ^ ((r & 7) << 3);
      GLDS(w2t + (long)r * 512 + nc * 128 + col, S1 + ch * 8);
    }
    __syncthreads();                           // H + W2c ready
    #pragma unroll
    for (int kk = 0; kk < 128; kk += 32) {
      bf16x8 af[4], bfr[4];
      #pragma unroll
      for (int mi = 0; mi < 4; mi++) {
        int R = m_off + mi*16 + lr;
        af[mi] = *(const bf16x8*)&S0[R*128 + ((kk + lk) ^ ((R & 7) << 3))];
      }
      #pragma unroll
      for (int ni = 0; ni < 4; ni++) {
        int R = n_off + ni*16 + lr;
        bfr[ni] = *(const bf16x8*)&S1[R*128 + ((kk + lk) ^ ((R & 7) << 3))];
      }
      #pragma unroll
      for (int mi = 0; mi < 4; mi++)
        #pragma unroll
        for (int ni = 0; ni < 4; ni++)
          acc_o[mi][ni] = __builtin_amdgcn_mfma_f32_16x16x32_bf16(
              af[mi], bfr[ni], acc_o[mi][ni], 0, 0, 0);
    }
  }

  // epilogue: x RMW (bf16) + optional fused LN1 -> shifted-window scatter
  float (*Cf)[128] = (float(*)[128])S0;
  #pragma unroll
  for (int half = 0; half < 2; half++) {
    __syncthreads();
    if ((wv >> 1) == half) {
      #pragma unroll
      for (int mi = 0; mi < 4; mi++)
        #pragma unroll
        for (int ni = 0; ni < 4; ni++)
          #pragma unroll
          for (int j = 0; j < 4; j++) {
            int lrow = mi*16 + 4*g + j;
            int col  = n_off + ni*16 + lr;
            Cf[lrow][col ^ ((lrow & 7) << 2)] = acc_o[mi][ni][j];
          }
    }
    __syncthreads();
    #pragma unroll
    for (int jj = 0; jj < 8; jj++) {
      int ch = tid + jj * 256;
      int r = ch >> 5, c4 = ch & 31;
      float4 v = *(const float4*)&Cf[r][(c4*4) ^ ((r & 7) << 2)];
      int t = row0 + half*64 + r;
      int gcol = c4*4;
      float4 b4 = *(const float4*)&b2[gcol];
      uint2 cur = *(const uint2*)&xrmw[(long)t * 128 + gcol];
      float o0 = blo(cur.x) + v.x + b4.x;
      float o1 = bhi(cur.x) + v.y + b4.y;
      float o2v = blo(cur.y) + v.z + b4.z;
      float o3 = bhi(cur.y) + v.w + b4.w;
      uint2 xw;
      xw.x = (u32)f2b(o0) | ((u32)f2b(o1) << 16);
      xw.y = (u32)f2b(o2v) | ((u32)f2b(o3) << 16);
      *(uint2*)(xrmw + (long)t * 128 + gcol) = xw;
      if (WRITE_LN) {
        float s = o0 + o1 + o2v + o3;
        float s2 = o0*o0 + o1*o1 + o2v*o2v + o3*o3;
        #pragma unroll
        for (int o = 1; o <= 16; o <<= 1) { s += __shfl_xor(s, o); s2 += __shfl_xor(s2, o); }
        float mean = s * 0.0078125f;
        float var  = s2 * 0.0078125f - mean * mean;
        float rstd = rsqrtf(var + 1e-5f);
        float4 g4  = *(const float4*)&lng[gcol];
        float4 bb4 = *(const float4*)&lnb[gcol];
        // linear token -> shifted-window position (shift -3 mod 56 both axes)
        int b_ = t / 3136; int rem = t - b_ * 3136;
        int hh = rem / 56, ww = rem - hh * 56;
        int hs = hh + 53; if (hs >= 56) hs -= 56;
        int ws = ww + 53; if (ws >= 56) ws -= 56;
        int gg = (hs / 7) * 8 + (ws / 7);
        int nn = (hs % 7) * 7 + (ws % 7);
        long dst = ((long)(b_ * 64 + gg) * 49 + nn) * 128 + gcol;
        uint2 lo2;
        lo2.x = (u32)f2b((o0 - mean) * rstd * g4.x + bb4.x) |
                ((u32)f2b((o1 - mean) * rstd * g4.y + bb4.y) << 16);
        lo2.y = (u32)f2b((o2v - mean) * rstd * g4.z + bb4.z) |
                ((u32)f2b((o3 - mean) * rstd * g4.w + bb4.w) << 16);
        *(uint2*)(lnout + dst) = lo2;
      }
    }
  }
}

extern "C" void kernel_launch(void* const* d_in, const int* in_sizes, int n_in,
                              void* d_out, int out_size, void* d_ws, size_t ws_size,
                              hipStream_t stream)
{
  const float* x_in   = (const float*)d_in[0];
  const float* ln1_g  = (const float*)d_in[1];
  const float* ln1_b  = (const float*)d_in[2];
  const float* qkv_w  = (const float*)d_in[3];
  const float* qkv_b  = (const float*)d_in[4];
  const float* proj_w = (const float*)d_in[5];
  const float* proj_b = (const float*)d_in[6];
  const float* ln2_g  = (const float*)d_in[7];
  const float* ln2_b  = (const float*)d_in[8];
  const float* w1     = (const float*)d_in[9];
  const float* b1     = (const float*)d_in[10];
  const float* w2     = (const float*)d_in[11];
  const float* b2     = (const float*)d_in[12];
  const float* dsg    = (const float*)d_in[13];
  const float* dsb    = (const float*)d_in[14];
  const float* dsw    = (const float*)d_in[15];

  // workspace carve (~360 MB), all-bf16 activations
  u16* x_ws     = (u16*)d_ws;                            // [MTOK][128] residual
  u16* buf_h    = x_ws + (long)MTOK * 128;               // [MTOK][128] LN1 out / attn O
  u16* xh       = buf_h + (long)MTOK * 128;              // [MTOK][128] LN2 out
  u16* buf_big  = xh + (long)MTOK * 128;                 // [MTOK][512] qkv / ds rows
  u16* wts      = buf_big + (long)MTOK * 512;
  u16* qkv_wt   = wts;                                   // [L][384][128]
  u16* proj_wt  = qkv_wt  + 2 * 49152;                   // [L][128][128]
  u16* w1t      = proj_wt + 2 * 16384;                   // [L][512][128]
  u16* w2t      = w1t     + 2 * 65536;                   // [L][128][512]
  u16* ds_wt    = w2t     + 2 * 65536;                   // [256][512]

  for (int i = 0; i < 2; i++) {
    transpose_cvt<<<(49152+255)/256, 256, 0, stream>>>(qkv_w  + i*49152, qkv_wt  + i*49152, 128, 384);
    transpose_cvt<<<(16384+255)/256, 256, 0, stream>>>(proj_w + i*16384, proj_wt + i*16384, 128, 128);
    transpose_cvt<<<(65536+255)/256, 256, 0, stream>>>(w1     + i*65536, w1t     + i*65536, 128, 512);
    transpose_cvt<<<(65536+255)/256, 256, 0, stream>>>(w2     + i*65536, w2t     + i*65536, 512, 128);
  }
  transpose_cvt<<<(131072+255)/256, 256, 0, stream>>>(dsw, ds_wt, 512, 256);

  // layer 0
  ln0_kernel<<<MTOK/4, 256, 0, stream>>>(x_in, ln1_g, ln1_b, buf_h);
  gemm_kernel<128,0,0><<<dim3(MTOK/128, 3), 256, 0, stream>>>(
      buf_h, qkv_wt, qkv_b, 384, buf_big, nullptr, nullptr, nullptr, 0,
      nullptr, nullptr, nullptr);
  attn_mfma<0><<<4096, 256, 0, stream>>>(buf_big, buf_h);
  gemm_kernel<128,2,1><<<dim3(MTOK/128, 1), 256, 0, stream>>>(
      buf_h, proj_wt, proj_b, 128, nullptr, nullptr, x_ws, x_in, 0,
      ln2_g, ln2_b, xh);
  mlp_kernel<1><<<MTOK/128, 256, 0, stream>>>(
      xh, w1t, b1, w2t, b2, x_ws, ln1_g + 128, ln1_b + 128, buf_h);

  // layer 1 (shifted)
  gemm_kernel<128,0,0><<<dim3(MTOK/128, 3), 256, 0, stream>>>(
      buf_h, qkv_wt + 49152, qkv_b + 384, 384, buf_big, nullptr, nullptr, nullptr, 0,
      nullptr, nullptr, nullptr);
  attn_mfma<1><<<4096, 256, 0, stream>>>(buf_big, buf_h);
  gemm_kernel<128,2,0><<<dim3(MTOK/128, 1), 256, 0, stream>>>(
      buf_h, proj_wt + 16384, proj_b + 128, 128, nullptr, nullptr, x_ws, nullptr, 1,
      ln2_g + 128, ln2_b + 128, xh);
  mlp_kernel<0><<<MTOK/128, 256, 0, stream>>>(
      xh, w1t + 65536, b1 + 512, w2t + 65536, b2 + 128, x_ws,
      nullptr, nullptr, nullptr);

  // downsample
  ds_ln_kernel<<<DSTOK/4, 256, 0, stream>>>(x_ws, dsg, dsb, buf_big);
  gemm_kernel<512,4,0><<<dim3(DSTOK/128, 2), 256, 0, stream>>>(
      buf_big, ds_wt, nullptr, 256, nullptr, (float*)d_out, nullptr, nullptr, 0,
      nullptr, nullptr, nullptr);
}